// Round 21
// baseline (356.713 us; speedup 1.0000x reference)
//
#include <hip/hip_runtime.h>
#include <cmath>

namespace {
constexpr int TT = 100;
constexpr int B = 512;
constexpr int NIN = 512;
constexpr int NOUT = 512;
constexpr int NEURONS = B * NOUT;  // 262144
constexpr int K3B = 3 * NIN;       // 1536 i8 per A row (3 digit planes)
// Fragment-chunk geometry: chunk = 16 rows x 64 k-bytes = 1024B.
// Intra-chunk granule [fq][fr]: loc = fq*256 + fr*16 (conflict-free ds_read).
// A layout: [rt][p][c][g]*1024, B layout: [nt][c][g]*1024.
// v10 gemm: 128x128 tile, BK=64, 24 steps, quad-buffered LDS + counted vmcnt.
// v2 scan: 2 adjacent neurons per thread (2 independent chains, float2 I/O).

constexpr double D_I0 = 1e-3;
constexpr double D_KAPPA = (0.75 + 0.66) / 2.0;
constexpr double D_UT = 25.0e-3;
constexpr float F_I0 = (float)D_I0;
constexpr float F_TAU_AMPA = (float)(2e-3 * D_UT / (D_KAPPA * 20.0 * D_I0));
constexpr float F_TAU_GABA = (float)(2e-3 * D_UT / (D_KAPPA * 5.0 * D_I0));
constexpr float F_TAU_SOMA = (float)(2e-3 * D_UT / (D_KAPPA * 5.0 * D_I0));
constexpr float F_TAU_AHP  = (float)(4e-3 * D_UT / (D_KAPPA * 2.0 * D_I0));
constexpr float F_DPI_TAU  = (float)(5.0 * D_I0);
constexpr float F_RESET    = (float)(1.2 * D_I0);
constexpr float F_VR       = (float)(5.0 * D_I0 + D_I0);
constexpr float F_TH       = (float)(2000.0 * D_I0);
constexpr float F_PFB_TH   = (float)(1000.0 * D_I0);
constexpr float F_ALPHA    = 4.0f;
constexpr float F_AMPA_GAIN = (float)(4.0 * 100.0 * D_I0);
constexpr float F_GABA_GAIN = (float)(4.0 * 100.0 * D_I0);
constexpr float F_AHP_GAIN  = (float)(4.0 * 2.0 * D_I0);
constexpr float F_AHP_JUMP  = (float)(4.0 * D_I0);
constexpr float F_PFB_NORM  = (float)(20.0 * D_I0);
constexpr float F_PFB_GAIN  = (float)(100.0 * D_I0);
constexpr float F_ALPHA_DPI = (float)(4.0 * (5.0 * D_I0));
constexpr float F_DT = 1e-3f;
constexpr float F_INIT_MEM = (float)(1.1 * D_I0);
constexpr float F_INV223 = 1.1920928955078125e-7f;  // 2^-23
constexpr unsigned BIAS_MUL = (1u << 14) + (1u << 22);
}  // namespace

typedef __attribute__((ext_vector_type(4))) int i32x4;

__device__ __forceinline__ void gload_lds16(const void* g, void* l) {
  __builtin_amdgcn_global_load_lds(
      (const __attribute__((address_space(1))) void*)g,
      (__attribute__((address_space(3))) void*)l, 16, 0, 0);
}

#define WAITVM(N) asm volatile("s_waitcnt vmcnt(" #N ")" ::: "memory")

// Chunked WT (granule [fq][fr]): byte w[k][n] ->
// [n>>7]*65536 + (k8>>3)*8192 + ((n>>4)&7)*1024 + ((k8&7)>>1)*256 + (n&15)*16 + (k8&1)*8.
__global__ __launch_bounds__(256) void build_wt(
    const float* __restrict__ Wa, const float* __restrict__ Wg,
    unsigned char* __restrict__ WTa, unsigned char* __restrict__ WTg) {
  const int t = blockIdx.x * 256 + threadIdx.x;  // 65536 threads
  const float* W = (t >> 15) ? Wg : Wa;
  unsigned char* O = (t >> 15) ? WTg : WTa;
  const int r = t & 32767;
  const int n = r >> 6, k8 = r & 63;
  unsigned char b[8];
#pragma unroll
  for (int j = 0; j < 8; ++j)
    b[j] = (unsigned char)(int)rintf(W[(size_t)(k8 * 8 + j) * 512 + n]);
  const size_t addr = (size_t)(n >> 7) * 65536 + (k8 >> 3) * 8192 +
                      ((n >> 4) & 7) * 1024 +
                      ((k8 & 7) >> 1) * 256 + (n & 15) * 16 + (k8 & 1) * 8;
  *(unsigned long long*)(O + addr) = *(unsigned long long*)b;
}

// colsum[z*512+n] = sum_k rint(W_z[k][n]); runs once.
__global__ __launch_bounds__(256) void colsum_w(
    const float* __restrict__ Wa, const float* __restrict__ Wg,
    int* __restrict__ colsum) {
  const int t = blockIdx.x * 256 + threadIdx.x;  // 1024 threads
  const int z = t >> 9, n = t & 511;
  const float* W = z ? Wg : Wa;
  int s = 0;
  for (int k = 0; k < 512; ++k) s += (int)rintf(W[(size_t)k * 512 + n]);
  colsum[t] = s;
}

// split3 (granule [fq][fr]): in-chunk loc = q*256 + rl*16.
// k = rint(x*2^23); p0=k&127, p1=((k>>7)&255)-128, p2=((k>>15)&255)-128.
__global__ __launch_bounds__(256) void split3(
    const float* __restrict__ XA, const float* __restrict__ XG,
    unsigned char* __restrict__ A4a, unsigned char* __restrict__ A4g, int nwpi) {
  const int wid = (blockIdx.x * 256 + threadIdx.x) >> 6;
  const int l = threadIdx.x & 63;
  const float* X = XA;
  unsigned char* O = A4a;
  int w = wid;
  if (w >= nwpi) { X = XG; O = A4g; w -= nwpi; }
  const int rt = w >> 6, rem = w & 63, c = rem >> 3, g = rem & 7;
  const int rl = l >> 2, q = l & 3;
  const float* src = X + (size_t)(rt * 128 + g * 16 + rl) * 512 + c * 64 + q * 16;
  float a[16];
#pragma unroll
  for (int j = 0; j < 4; ++j) {
    const float4 v = *(const float4*)(src + j * 4);
    a[j * 4 + 0] = v.x; a[j * 4 + 1] = v.y; a[j * 4 + 2] = v.z; a[j * 4 + 3] = v.w;
  }
  unsigned int k[16];
#pragma unroll
  for (int e = 0; e < 16; ++e) k[e] = (unsigned int)rintf(a[e] * 8388608.0f);
  unsigned char* base = O + (size_t)rt * 196608 + c * 8192 + g * 1024 + q * 256 + rl * 16;
  unsigned int u[4];
#pragma unroll
  for (int j = 0; j < 4; ++j)
    u[j] = (k[4 * j] & 127u) | ((k[4 * j + 1] & 127u) << 8) |
           ((k[4 * j + 2] & 127u) << 16) | ((k[4 * j + 3] & 127u) << 24);
  *(uint4*)(base) = make_uint4(u[0], u[1], u[2], u[3]);
#pragma unroll
  for (int j = 0; j < 4; ++j)
    u[j] = (((k[4 * j] >> 7) - 128u) & 255u) | ((((k[4 * j + 1] >> 7) - 128u) & 255u) << 8) |
           ((((k[4 * j + 2] >> 7) - 128u) & 255u) << 16) | ((((k[4 * j + 3] >> 7) - 128u) & 255u) << 24);
  *(uint4*)(base + 65536) = make_uint4(u[0], u[1], u[2], u[3]);
#pragma unroll
  for (int j = 0; j < 4; ++j)
    u[j] = (((k[4 * j] >> 15) - 128u) & 255u) | ((((k[4 * j + 1] >> 15) - 128u) & 255u) << 8) |
           ((((k[4 * j + 2] >> 15) - 128u) & 255u) << 16) | ((((k[4 * j + 3] >> 15) - 128u) & 255u) << 24);
  *(uint4*)(base + 131072) = make_uint4(u[0], u[1], u[2], u[3]);
}

// Exact GEMM v10 (R20-verified): quad-buffered LDS, depth-3 prefetch,
// raw s_barrier + counted vmcnt. INC = RN((digits@W Horner)+bias)*2^-23.
__global__ __launch_bounds__(256) void gemm_i8_v10(
    const unsigned char* __restrict__ A4a, const unsigned char* __restrict__ A4g,
    const unsigned char* __restrict__ WTa, const unsigned char* __restrict__ WTg,
    const int* __restrict__ colsum,
    float* __restrict__ INCa, float* __restrict__ INCg, int nwg) {
  __shared__ __align__(16) unsigned char LDS[65536];
  unsigned char* Al = LDS;           // 4 x 8KB A bufs
  unsigned char* Bl = LDS + 32768;   // 4 x 8KB B bufs
  const int bid = blockIdx.x;
  const int L = (bid & 7) * (nwg >> 3) + (bid >> 3);  // nwg % 8 == 0
  const int m = L >> 3, sub = L & 7;
  const int n = sub & 3, z = sub >> 2;
  const unsigned char* A4 = (z ? A4g : A4a) + (size_t)m * 196608;
  const unsigned char* Bg = (z ? WTg : WTa) + (size_t)n * 65536;
  float* C = z ? INCg : INCa;

  const int tid = threadIdx.x;
  const int lane = tid & 63, wave = tid >> 6;
  const int wr = wave >> 1, wc = wave & 1;  // 2x2 waves: 64x64 out each
  const int fr = lane & 15, fq = lane >> 4;
  const int goff = tid * 16;
  const int woff = wave * 1024;
  const int floc = fq * 256 + fr * 16;

#define STAGE(t)                                                            \
  {                                                                         \
    const int aoff_ = (2 - ((t) >> 3)) * 65536 + ((t) & 7) * 8192;          \
    const int boff_ = ((t) & 7) * 8192;                                     \
    const int lb_ = ((t) & 3) * 8192 + woff;                                \
    gload_lds16(A4 + aoff_ + goff, Al + lb_);                               \
    gload_lds16(A4 + aoff_ + 4096 + goff, Al + lb_ + 4096);                 \
    gload_lds16(Bg + boff_ + goff, Bl + lb_);                               \
    gload_lds16(Bg + boff_ + 4096 + goff, Bl + lb_ + 4096);                 \
  }

  STAGE(0) STAGE(1) STAGE(2)

  i32x4 acc[4][4] = {};
#pragma unroll
  for (int s = 0; s < 24; ++s) {
    if (s <= 21) WAITVM(8);
    else if (s == 22) WAITVM(4);
    else WAITVM(0);
    __builtin_amdgcn_s_barrier();
    asm volatile("" ::: "memory");
    __builtin_amdgcn_sched_barrier(0);
    if (s + 3 < 24) STAGE(s + 3)
    {
      const int b = (s & 3) * 8192;
      i32x4 af[4], bf[4];
#pragma unroll
      for (int fm = 0; fm < 4; ++fm)
        af[fm] = *(const i32x4*)&Al[b + (wr * 4 + fm) * 1024 + floc];
#pragma unroll
      for (int fn = 0; fn < 4; ++fn)
        bf[fn] = *(const i32x4*)&Bl[b + (wc * 4 + fn) * 1024 + floc];
#pragma unroll
      for (int fm = 0; fm < 4; ++fm)
#pragma unroll
        for (int fn = 0; fn < 4; ++fn)
          acc[fm][fn] = __builtin_amdgcn_mfma_i32_16x16x64_i8(
              af[fm], bf[fn], acc[fm][fn], 0, 0, 0);
    }
    if (s == 7) {
#pragma unroll
      for (int fm = 0; fm < 4; ++fm)
#pragma unroll
        for (int fn = 0; fn < 4; ++fn) acc[fm][fn] = acc[fm][fn] << 8;
    }
    if (s == 15) {
#pragma unroll
      for (int fm = 0; fm < 4; ++fm)
#pragma unroll
        for (int fn = 0; fn < 4; ++fn) acc[fm][fn] = acc[fm][fn] << 7;
    }
  }
#undef STAGE
  __syncthreads();

  const int crow0 = m * 128 + wr * 64;
  const int ccol0 = n * 128 + wc * 64;
  unsigned bias[4];
#pragma unroll
  for (int fn = 0; fn < 4; ++fn)
    bias[fn] = BIAS_MUL * (unsigned)colsum[z * 512 + ccol0 + fn * 16 + fr];
  float* scratch = (float*)LDS + wave * (16 * 68);
  const int erow = lane >> 4;
  const int ecol = (lane & 15) * 4;
#pragma unroll
  for (int fm = 0; fm < 4; ++fm) {
#pragma unroll
    for (int fn = 0; fn < 4; ++fn)
#pragma unroll
      for (int r = 0; r < 4; ++r) {
        const unsigned tot = (unsigned)acc[fm][fn][r] + bias[fn];
        scratch[(fq * 4 + r) * 68 + fn * 16 + fr] = (float)tot * F_INV223;
      }
    float4 rows[4];
#pragma unroll
    for (int j = 0; j < 4; ++j)
      rows[j] = *(const float4*)&scratch[(erow + 4 * j) * 68 + ecol];
#pragma unroll
    for (int j = 0; j < 4; ++j) {
      const int grow = crow0 + fm * 16 + erow + 4 * j;
      *(float4*)&C[(size_t)grow * NOUT + ccol0 + ecol] = rows[j];
    }
  }
}

// neuron_scan v2: each thread owns TWO adjacent neurons (2i, 2i+1) — two
// independent dependency chains fill VALU issue bubbles; float2 I/O halves
// load/store insts. Per-neuron op sequence UNCHANGED (bit-exact vs R20).
__global__ __launch_bounds__(256) void neuron_scan2(
    const float* __restrict__ inca, const float* __restrict__ incg,
    float* __restrict__ Sout, float* __restrict__ state, int tc, int first) {
  const int p = blockIdx.x * 256 + threadIdx.x;  // pair index, 2 neurons
  const int i0 = 2 * p;
  float mem0, am0, ga0, ah0, rf0;
  float mem1, am1, ga1, ah1, rf1;
  if (first) {
    mem0 = mem1 = F_INIT_MEM;
    am0 = am1 = F_I0;
    ga0 = ga1 = F_I0;
    ah0 = ah1 = 0.0f;
    rf0 = rf1 = 0.0f;
  } else {
    float2 v;
    v = *(const float2*)&state[i0];               mem0 = v.x; mem1 = v.y;
    v = *(const float2*)&state[NEURONS + i0];     am0 = v.x;  am1 = v.y;
    v = *(const float2*)&state[2 * NEURONS + i0]; ga0 = v.x;  ga1 = v.y;
    v = *(const float2*)&state[3 * NEURONS + i0]; ah0 = v.x;  ah1 = v.y;
    v = *(const float2*)&state[4 * NEURONS + i0]; rf0 = v.x;  rf1 = v.y;
  }
  for (int t = 0; t < tc; ++t) {
    const float2 va = *(const float2*)&inca[(size_t)t * NEURONS + i0];
    const float2 vg = *(const float2*)&incg[(size_t)t * NEURONS + i0];
    const float xa0 = F_AMPA_GAIN * va.x, xa1 = F_AMPA_GAIN * va.y;
    const float xg0 = F_GABA_GAIN * vg.x, xg1 = F_GABA_GAIN * vg.y;

    const float pfb0 = F_PFB_GAIN / (1.0f + expf(-(mem0 - F_PFB_TH) / F_PFB_NORM));
    const float pfb1 = F_PFB_GAIN / (1.0f + expf(-(mem1 - F_PFB_TH) / F_PFB_NORM));
    const float dah0 = (-F_AHP_GAIN - ah0) / (F_TAU_AHP * (1.0f + F_AHP_GAIN / ah0));
    const float dah1 = (-F_AHP_GAIN - ah1) / (F_TAU_AHP * (1.0f + F_AHP_GAIN / ah1));
    const float Iin0 = fmaxf(am0 - ga0 + F_I0, F_I0);
    const float Iin1 = fmaxf(am1 - ga1 + F_I0, F_I0);
    const float Is0 = F_VR + ah0 - pfb0;
    const float Is1 = F_VR + ah1 - pfb1;
    const float dm0 = (F_ALPHA * (Iin0 - Is0) - Is0 * mem0 / F_DPI_TAU)
                    / (F_TAU_SOMA * (1.0f + F_ALPHA_DPI / mem0));
    const float dm1 = (F_ALPHA * (Iin1 - Is1) - Is1 * mem1 / F_DPI_TAU)
                    / (F_TAU_SOMA * (1.0f + F_ALPHA_DPI / mem1));
    const float dam0 = (F_I0 - am0) / F_TAU_AMPA;
    const float dam1 = (F_I0 - am1) / F_TAU_AMPA;
    am0 = am0 + xa0;
    am1 = am1 + xa1;
    const float dga0 = (F_I0 - ga0) / F_TAU_GABA;
    const float dga1 = (F_I0 - ga1) / F_TAU_GABA;
    ga0 = ga0 + xg0;
    ga1 = ga1 + xg1;
    rf0 = rf0 - (rf0 > 0.0f ? 1.0f : 0.0f);
    rf1 = rf1 - (rf1 > 0.0f ? 1.0f : 0.0f);
    mem0 = mem0 + F_DT * dm0 * (rf0 <= 0.0f ? 1.0f : 0.0f);
    mem1 = mem1 + F_DT * dm1 * (rf1 <= 0.0f ? 1.0f : 0.0f);
    ah0 = ah0 + F_DT * dah0;
    ah1 = ah1 + F_DT * dah1;
    am0 = am0 + F_DT * dam0;
    am1 = am1 + F_DT * dam1;
    ga0 = ga0 + F_DT * dga0;
    ga1 = ga1 + F_DT * dga1;
    const float S0 = (mem0 - F_TH) > 0.0f ? 1.0f : 0.0f;
    const float S1 = (mem1 - F_TH) > 0.0f ? 1.0f : 0.0f;
    rf0 = rf0 + floorf(S0 * 5.0f);
    rf1 = rf1 + floorf(S1 * 5.0f);
    ah0 = ah0 + F_AHP_JUMP * S0;
    ah1 = ah1 + F_AHP_JUMP * S1;
    mem0 = F_RESET * S0 + mem0 * (1.0f - S0);
    mem1 = F_RESET * S1 + mem1 * (1.0f - S1);
    mem0 = fmaxf(mem0, F_I0);
    mem1 = fmaxf(mem1, F_I0);
    *(float2*)&Sout[(size_t)t * NEURONS + i0] = make_float2(S0, S1);
  }
  *(float2*)&state[i0] = make_float2(mem0, mem1);
  *(float2*)&state[NEURONS + i0] = make_float2(am0, am1);
  *(float2*)&state[2 * NEURONS + i0] = make_float2(ga0, ga1);
  *(float2*)&state[3 * NEURONS + i0] = make_float2(ah0, ah1);
  *(float2*)&state[4 * NEURONS + i0] = make_float2(rf0, rf1);
}

extern "C" void kernel_launch(void* const* d_in, const int* in_sizes, int n_in,
                              void* d_out, int out_size, void* d_ws, size_t ws_size,
                              hipStream_t stream) {
  const float* XA = (const float*)d_in[0];
  const float* XG = (const float*)d_in[1];
  const float* WA = (const float*)d_in[2];
  const float* WG = (const float*)d_in[3];
  float* S = (float*)d_out;

  int tc = 1;
  const int cands[8] = {100, 50, 25, 20, 10, 5, 2, 1};
  for (int i = 0; i < 8; ++i) {
    const size_t need = 5771264ull + (size_t)cands[i] * 3670016ull;
    if (need <= ws_size) { tc = cands[i]; break; }
  }

  unsigned char* WTa = (unsigned char*)d_ws;
  unsigned char* WTg = WTa + (size_t)NOUT * 512;
  int* colsum = (int*)(WTg + (size_t)NOUT * 512);
  unsigned char* A4a = (unsigned char*)(colsum + 1024);
  unsigned char* A4g = A4a + (size_t)tc * B * K3B;
  float* INCa  = (float*)(A4g + (size_t)tc * B * K3B);
  float* INCg  = INCa + (size_t)tc * NEURONS;
  float* state = INCg + (size_t)tc * NEURONS;

  build_wt<<<256, 256, 0, stream>>>(WA, WG, WTa, WTg);
  colsum_w<<<4, 256, 0, stream>>>(WA, WG, colsum);

  const int nwpi = tc * 256;              // split waves per input
  const int splitBlocks = nwpi / 2;       // 2 inputs, 4 waves/block
  const int nm = tc * B / 128;            // 128-row m-tiles
  const int nwg = nm * 8;                 // x4 n-tiles x2 z
  const int nch = TT / tc;
  for (int c = 0; c < nch; ++c) {
    const size_t inOff = (size_t)c * tc * B * NIN;
    split3<<<splitBlocks, 256, 0, stream>>>(XA + inOff, XG + inOff, A4a, A4g, nwpi);
    gemm_i8_v10<<<nwg, 256, 0, stream>>>(A4a, A4g, WTa, WTg, colsum, INCa, INCg, nwg);
    neuron_scan2<<<NEURONS / 512, 256, 0, stream>>>(
        INCa, INCg, S + (size_t)c * tc * NEURONS, state, tc, c == 0 ? 1 : 0);
  }
}

// Round 22
// 355.006 us; speedup vs baseline: 1.0048x; 1.0048x over previous
//
#include <hip/hip_runtime.h>
#include <cmath>

namespace {
constexpr int TT = 100;
constexpr int B = 512;
constexpr int NIN = 512;
constexpr int NOUT = 512;
constexpr int NEURONS = B * NOUT;  // 262144
constexpr int K3B = 3 * NIN;       // 1536 i8 per A row (3 digit planes)
// Fragment-chunk geometry: chunk = 16 rows x 64 k-bytes = 1024B.
// Intra-chunk granule [fq][fr]: loc = fq*256 + fr*16 (conflict-free ds_read).
// A layout: [rt][p][c][g]*1024, B layout: [nt][c][g]*1024.
// v10b gemm: 128x128 tile, BK=64, 24 steps, TRIPLE-buffered LDS (48KB ->
// 3 blocks/CU), depth-2 prefetch, raw s_barrier + counted vmcnt (T3+T4).

constexpr double D_I0 = 1e-3;
constexpr double D_KAPPA = (0.75 + 0.66) / 2.0;
constexpr double D_UT = 25.0e-3;
constexpr float F_I0 = (float)D_I0;
constexpr float F_TAU_AMPA = (float)(2e-3 * D_UT / (D_KAPPA * 20.0 * D_I0));
constexpr float F_TAU_GABA = (float)(2e-3 * D_UT / (D_KAPPA * 5.0 * D_I0));
constexpr float F_TAU_SOMA = (float)(2e-3 * D_UT / (D_KAPPA * 5.0 * D_I0));
constexpr float F_TAU_AHP  = (float)(4e-3 * D_UT / (D_KAPPA * 2.0 * D_I0));
constexpr float F_DPI_TAU  = (float)(5.0 * D_I0);
constexpr float F_RESET    = (float)(1.2 * D_I0);
constexpr float F_VR       = (float)(5.0 * D_I0 + D_I0);
constexpr float F_TH       = (float)(2000.0 * D_I0);
constexpr float F_PFB_TH   = (float)(1000.0 * D_I0);
constexpr float F_ALPHA    = 4.0f;
constexpr float F_AMPA_GAIN = (float)(4.0 * 100.0 * D_I0);
constexpr float F_GABA_GAIN = (float)(4.0 * 100.0 * D_I0);
constexpr float F_AHP_GAIN  = (float)(4.0 * 2.0 * D_I0);
constexpr float F_AHP_JUMP  = (float)(4.0 * D_I0);
constexpr float F_PFB_NORM  = (float)(20.0 * D_I0);
constexpr float F_PFB_GAIN  = (float)(100.0 * D_I0);
constexpr float F_ALPHA_DPI = (float)(4.0 * (5.0 * D_I0));
constexpr float F_DT = 1e-3f;
constexpr float F_INIT_MEM = (float)(1.1 * D_I0);
constexpr float F_INV223 = 1.1920928955078125e-7f;  // 2^-23
constexpr unsigned BIAS_MUL = (1u << 14) + (1u << 22);
}  // namespace

typedef __attribute__((ext_vector_type(4))) int i32x4;

__device__ __forceinline__ void gload_lds16(const void* g, void* l) {
  __builtin_amdgcn_global_load_lds(
      (const __attribute__((address_space(1))) void*)g,
      (__attribute__((address_space(3))) void*)l, 16, 0, 0);
}

#define WAITVM(N) asm volatile("s_waitcnt vmcnt(" #N ")" ::: "memory")

// Chunked WT (granule [fq][fr]): byte w[k][n] ->
// [n>>7]*65536 + (k8>>3)*8192 + ((n>>4)&7)*1024 + ((k8&7)>>1)*256 + (n&15)*16 + (k8&1)*8.
__global__ __launch_bounds__(256) void build_wt(
    const float* __restrict__ Wa, const float* __restrict__ Wg,
    unsigned char* __restrict__ WTa, unsigned char* __restrict__ WTg) {
  const int t = blockIdx.x * 256 + threadIdx.x;  // 65536 threads
  const float* W = (t >> 15) ? Wg : Wa;
  unsigned char* O = (t >> 15) ? WTg : WTa;
  const int r = t & 32767;
  const int n = r >> 6, k8 = r & 63;
  unsigned char b[8];
#pragma unroll
  for (int j = 0; j < 8; ++j)
    b[j] = (unsigned char)(int)rintf(W[(size_t)(k8 * 8 + j) * 512 + n]);
  const size_t addr = (size_t)(n >> 7) * 65536 + (k8 >> 3) * 8192 +
                      ((n >> 4) & 7) * 1024 +
                      ((k8 & 7) >> 1) * 256 + (n & 15) * 16 + (k8 & 1) * 8;
  *(unsigned long long*)(O + addr) = *(unsigned long long*)b;
}

// colsum[z*512+n] = sum_k rint(W_z[k][n]); runs once.
__global__ __launch_bounds__(256) void colsum_w(
    const float* __restrict__ Wa, const float* __restrict__ Wg,
    int* __restrict__ colsum) {
  const int t = blockIdx.x * 256 + threadIdx.x;  // 1024 threads
  const int z = t >> 9, n = t & 511;
  const float* W = z ? Wg : Wa;
  int s = 0;
  for (int k = 0; k < 512; ++k) s += (int)rintf(W[(size_t)k * 512 + n]);
  colsum[t] = s;
}

// split3 (granule [fq][fr]): in-chunk loc = q*256 + rl*16.
// k = rint(x*2^23); p0=k&127, p1=((k>>7)&255)-128, p2=((k>>15)&255)-128.
__global__ __launch_bounds__(256) void split3(
    const float* __restrict__ XA, const float* __restrict__ XG,
    unsigned char* __restrict__ A4a, unsigned char* __restrict__ A4g, int nwpi) {
  const int wid = (blockIdx.x * 256 + threadIdx.x) >> 6;
  const int l = threadIdx.x & 63;
  const float* X = XA;
  unsigned char* O = A4a;
  int w = wid;
  if (w >= nwpi) { X = XG; O = A4g; w -= nwpi; }
  const int rt = w >> 6, rem = w & 63, c = rem >> 3, g = rem & 7;
  const int rl = l >> 2, q = l & 3;
  const float* src = X + (size_t)(rt * 128 + g * 16 + rl) * 512 + c * 64 + q * 16;
  float a[16];
#pragma unroll
  for (int j = 0; j < 4; ++j) {
    const float4 v = *(const float4*)(src + j * 4);
    a[j * 4 + 0] = v.x; a[j * 4 + 1] = v.y; a[j * 4 + 2] = v.z; a[j * 4 + 3] = v.w;
  }
  unsigned int k[16];
#pragma unroll
  for (int e = 0; e < 16; ++e) k[e] = (unsigned int)rintf(a[e] * 8388608.0f);
  unsigned char* base = O + (size_t)rt * 196608 + c * 8192 + g * 1024 + q * 256 + rl * 16;
  unsigned int u[4];
#pragma unroll
  for (int j = 0; j < 4; ++j)
    u[j] = (k[4 * j] & 127u) | ((k[4 * j + 1] & 127u) << 8) |
           ((k[4 * j + 2] & 127u) << 16) | ((k[4 * j + 3] & 127u) << 24);
  *(uint4*)(base) = make_uint4(u[0], u[1], u[2], u[3]);
#pragma unroll
  for (int j = 0; j < 4; ++j)
    u[j] = (((k[4 * j] >> 7) - 128u) & 255u) | ((((k[4 * j + 1] >> 7) - 128u) & 255u) << 8) |
           ((((k[4 * j + 2] >> 7) - 128u) & 255u) << 16) | ((((k[4 * j + 3] >> 7) - 128u) & 255u) << 24);
  *(uint4*)(base + 65536) = make_uint4(u[0], u[1], u[2], u[3]);
#pragma unroll
  for (int j = 0; j < 4; ++j)
    u[j] = (((k[4 * j] >> 15) - 128u) & 255u) | ((((k[4 * j + 1] >> 15) - 128u) & 255u) << 8) |
           ((((k[4 * j + 2] >> 15) - 128u) & 255u) << 16) | ((((k[4 * j + 3] >> 15) - 128u) & 255u) << 24);
  *(uint4*)(base + 131072) = make_uint4(u[0], u[1], u[2], u[3]);
}

// Exact GEMM v10b: triple-buffered LDS (3x8KB A + 3x8KB B = 48KB -> 3 blocks/CU,
// 12 waves), depth-2 prefetch, counted vmcnt (steady state 4, never 0 mid-loop).
// Per step s: WAITVM(stage s landed) -> s_barrier (also: buf[(s+2)%3]'s readers
// from step s-1 are done) -> issue STAGE(s+2) -> compute buf[s%3].
// INC = RN((digits @ W Horner) + bias) * 2^-23 — bit-identical to rounds 5-21.
__global__ __launch_bounds__(256) void gemm_i8_v10b(
    const unsigned char* __restrict__ A4a, const unsigned char* __restrict__ A4g,
    const unsigned char* __restrict__ WTa, const unsigned char* __restrict__ WTg,
    const int* __restrict__ colsum,
    float* __restrict__ INCa, float* __restrict__ INCg, int nwg) {
  __shared__ __align__(16) unsigned char LDS[49152];
  unsigned char* Al = LDS;           // 3 x 8KB A bufs
  unsigned char* Bl = LDS + 24576;   // 3 x 8KB B bufs
  const int bid = blockIdx.x;
  const int L = (bid & 7) * (nwg >> 3) + (bid >> 3);  // nwg % 8 == 0
  const int m = L >> 3, sub = L & 7;
  const int n = sub & 3, z = sub >> 2;
  const unsigned char* A4 = (z ? A4g : A4a) + (size_t)m * 196608;
  const unsigned char* Bg = (z ? WTg : WTa) + (size_t)n * 65536;
  float* C = z ? INCg : INCa;

  const int tid = threadIdx.x;
  const int lane = tid & 63, wave = tid >> 6;
  const int wr = wave >> 1, wc = wave & 1;  // 2x2 waves: 64x64 out each
  const int fr = lane & 15, fq = lane >> 4;
  const int goff = tid * 16;
  const int woff = wave * 1024;
  const int floc = fq * 256 + fr * 16;

#define STAGE(t)                                                            \
  {                                                                         \
    const int aoff_ = (2 - ((t) >> 3)) * 65536 + ((t) & 7) * 8192;          \
    const int boff_ = ((t) & 7) * 8192;                                     \
    const int lb_ = ((t) % 3) * 8192 + woff;                                \
    gload_lds16(A4 + aoff_ + goff, Al + lb_);                               \
    gload_lds16(A4 + aoff_ + 4096 + goff, Al + lb_ + 4096);                 \
    gload_lds16(Bg + boff_ + goff, Bl + lb_);                               \
    gload_lds16(Bg + boff_ + 4096 + goff, Bl + lb_ + 4096);                 \
  }

  // Prologue: stages 0,1 in flight (8 loads/thread outstanding).
  STAGE(0) STAGE(1)

  i32x4 acc[4][4] = {};
#pragma unroll
  for (int s = 0; s < 24; ++s) {
    // stage(s) landed; stage(s+1) (4 loads) may stay in flight.
    if (s <= 22) WAITVM(4);
    else WAITVM(0);
    __builtin_amdgcn_s_barrier();
    asm volatile("" ::: "memory");
    __builtin_amdgcn_sched_barrier(0);
    if (s + 2 < 24) STAGE(s + 2)  // buf[(s+2)%3] readers finished at step s-1
    {
      const int b = (s % 3) * 8192;
      i32x4 af[4], bf[4];
#pragma unroll
      for (int fm = 0; fm < 4; ++fm)
        af[fm] = *(const i32x4*)&Al[b + (wr * 4 + fm) * 1024 + floc];
#pragma unroll
      for (int fn = 0; fn < 4; ++fn)
        bf[fn] = *(const i32x4*)&Bl[b + (wc * 4 + fn) * 1024 + floc];
#pragma unroll
      for (int fm = 0; fm < 4; ++fm)
#pragma unroll
        for (int fn = 0; fn < 4; ++fn)
          acc[fm][fn] = __builtin_amdgcn_mfma_i32_16x16x64_i8(
              af[fm], bf[fn], acc[fm][fn], 0, 0, 0);
    }
    if (s == 7) {    // plane-2 done: Horner scale 2^8 (mod 2^32, exact)
#pragma unroll
      for (int fm = 0; fm < 4; ++fm)
#pragma unroll
        for (int fn = 0; fn < 4; ++fn) acc[fm][fn] = acc[fm][fn] << 8;
    }
    if (s == 15) {   // plane-1 done: scale 2^7
#pragma unroll
      for (int fm = 0; fm < 4; ++fm)
#pragma unroll
        for (int fn = 0; fn < 4; ++fn) acc[fm][fn] = acc[fm][fn] << 7;
    }
  }
#undef STAGE
  __syncthreads();  // full drain before epilogue overlays LDS

  // Epilogue (R9-verified): bias + convert; per-wave LDS transpose ->
  // coalesced 256B-row dwordx4 stores.
  // acc: col = lane&15 (+fn*16), row = fq*4+r (+fm*16)  [m89/m91]
  const int crow0 = m * 128 + wr * 64;
  const int ccol0 = n * 128 + wc * 64;
  unsigned bias[4];
#pragma unroll
  for (int fn = 0; fn < 4; ++fn)
    bias[fn] = BIAS_MUL * (unsigned)colsum[z * 512 + ccol0 + fn * 16 + fr];
  float* scratch = (float*)LDS + wave * (16 * 68);
  const int erow = lane >> 4;
  const int ecol = (lane & 15) * 4;
#pragma unroll
  for (int fm = 0; fm < 4; ++fm) {
#pragma unroll
    for (int fn = 0; fn < 4; ++fn)
#pragma unroll
      for (int r = 0; r < 4; ++r) {
        const unsigned tot = (unsigned)acc[fm][fn][r] + bias[fn];
        scratch[(fq * 4 + r) * 68 + fn * 16 + fr] = (float)tot * F_INV223;
      }
    float4 rows[4];
#pragma unroll
    for (int j = 0; j < 4; ++j)
      rows[j] = *(const float4*)&scratch[(erow + 4 * j) * 68 + ecol];
#pragma unroll
    for (int j = 0; j < 4; ++j) {
      const int grow = crow0 + fm * 16 + erow + 4 * j;
      *(float4*)&C[(size_t)grow * NOUT + ccol0 + ecol] = rows[j];
    }
  }
}

// neuron_scan v1 (R20-verified best: 142us, VALUBusy 77%, 16 waves/CU).
// One thread per neuron; tc timesteps in registers; matches JAX op-for-op.
__global__ __launch_bounds__(256) void neuron_scan(
    const float* __restrict__ inca, const float* __restrict__ incg,
    float* __restrict__ Sout, float* __restrict__ state, int tc, int first) {
  const int idx = blockIdx.x * 256 + threadIdx.x;
  float mem, ampa, gaba, ahp, refr;
  if (first) {
    mem = F_INIT_MEM; ampa = F_I0; gaba = F_I0; ahp = 0.0f; refr = 0.0f;
  } else {
    mem  = state[idx];
    ampa = state[NEURONS + idx];
    gaba = state[2 * NEURONS + idx];
    ahp  = state[3 * NEURONS + idx];
    refr = state[4 * NEURONS + idx];
  }
  for (int t = 0; t < tc; ++t) {
    const float xa = F_AMPA_GAIN * inca[(size_t)t * NEURONS + idx];
    const float xg = F_GABA_GAIN * incg[(size_t)t * NEURONS + idx];
    const float pfb = F_PFB_GAIN / (1.0f + expf(-(mem - F_PFB_TH) / F_PFB_NORM));
    const float dahp = (-F_AHP_GAIN - ahp) / (F_TAU_AHP * (1.0f + F_AHP_GAIN / ahp));
    const float Iin = fmaxf(ampa - gaba + F_I0, F_I0);
    const float Isum = F_VR + ahp - pfb;
    const float dmem = (F_ALPHA * (Iin - Isum) - Isum * mem / F_DPI_TAU)
                     / (F_TAU_SOMA * (1.0f + F_ALPHA_DPI / mem));
    const float dampa = (F_I0 - ampa) / F_TAU_AMPA;
    ampa = ampa + xa;
    const float dgaba = (F_I0 - gaba) / F_TAU_GABA;
    gaba = gaba + xg;
    refr = refr - (refr > 0.0f ? 1.0f : 0.0f);
    mem = mem + F_DT * dmem * (refr <= 0.0f ? 1.0f : 0.0f);
    ahp = ahp + F_DT * dahp;
    ampa = ampa + F_DT * dampa;
    gaba = gaba + F_DT * dgaba;
    const float S = (mem - F_TH) > 0.0f ? 1.0f : 0.0f;
    refr = refr + floorf(S * 5.0f);
    ahp = ahp + F_AHP_JUMP * S;
    mem = F_RESET * S + mem * (1.0f - S);
    mem = fmaxf(mem, F_I0);
    Sout[(size_t)t * NEURONS + idx] = S;
  }
  state[idx] = mem;
  state[NEURONS + idx] = ampa;
  state[2 * NEURONS + idx] = gaba;
  state[3 * NEURONS + idx] = ahp;
  state[4 * NEURONS + idx] = refr;
}

extern "C" void kernel_launch(void* const* d_in, const int* in_sizes, int n_in,
                              void* d_out, int out_size, void* d_ws, size_t ws_size,
                              hipStream_t stream) {
  const float* XA = (const float*)d_in[0];
  const float* XG = (const float*)d_in[1];
  const float* WA = (const float*)d_in[2];
  const float* WG = (const float*)d_in[3];
  float* S = (float*)d_out;

  int tc = 1;
  const int cands[8] = {100, 50, 25, 20, 10, 5, 2, 1};
  for (int i = 0; i < 8; ++i) {
    const size_t need = 5771264ull + (size_t)cands[i] * 3670016ull;
    if (need <= ws_size) { tc = cands[i]; break; }
  }

  unsigned char* WTa = (unsigned char*)d_ws;
  unsigned char* WTg = WTa + (size_t)NOUT * 512;
  int* colsum = (int*)(WTg + (size_t)NOUT * 512);
  unsigned char* A4a = (unsigned char*)(colsum + 1024);
  unsigned char* A4g = A4a + (size_t)tc * B * K3B;
  float* INCa  = (float*)(A4g + (size_t)tc * B * K3B);
  float* INCg  = INCa + (size_t)tc * NEURONS;
  float* state = INCg + (size_t)tc * NEURONS;

  build_wt<<<256, 256, 0, stream>>>(WA, WG, WTa, WTg);
  colsum_w<<<4, 256, 0, stream>>>(WA, WG, colsum);

  const int nwpi = tc * 256;              // split waves per input
  const int splitBlocks = nwpi / 2;       // 2 inputs, 4 waves/block
  const int nm = tc * B / 128;            // 128-row m-tiles
  const int nwg = nm * 8;                 // x4 n-tiles x2 z
  const int nch = TT / tc;
  for (int c = 0; c < nch; ++c) {
    const size_t inOff = (size_t)c * tc * B * NIN;
    split3<<<splitBlocks, 256, 0, stream>>>(XA + inOff, XG + inOff, A4a, A4g, nwpi);
    gemm_i8_v10b<<<nwg, 256, 0, stream>>>(A4a, A4g, WTa, WTg, colsum, INCa, INCg, nwg);
    neuron_scan<<<NEURONS / 256, 256, 0, stream>>>(
        INCa, INCg, S + (size_t)c * tc * NEURONS, state, tc, c == 0 ? 1 : 0);
  }
}

// Round 23
// 346.786 us; speedup vs baseline: 1.0286x; 1.0237x over previous
//
#include <hip/hip_runtime.h>
#include <cmath>

namespace {
constexpr int TT = 100;
constexpr int B = 512;
constexpr int NIN = 512;
constexpr int NOUT = 512;
constexpr int NEURONS = B * NOUT;  // 262144
constexpr int K3B = 3 * NIN;       // 1536 i8 per A row (3 digit planes)
// Fragment-chunk geometry: chunk = 16 rows x 64 k-bytes = 1024B.
// Intra-chunk granule [fq][fr]: loc = fq*256 + fr*16 (conflict-free ds_read).
// A layout: [rt][p][c][g]*1024, B layout: [nt][c][g]*1024.
// v10 gemm (R20-verified best): 128x128 tile, BK=64, 24 steps, QUAD-buffered
// LDS (64KB), depth-3 prefetch, raw s_barrier + counted vmcnt (T3+T4).
// scan v1 + depth-1 INC prefetch (loads for t+1 issue before compute of t).

constexpr double D_I0 = 1e-3;
constexpr double D_KAPPA = (0.75 + 0.66) / 2.0;
constexpr double D_UT = 25.0e-3;
constexpr float F_I0 = (float)D_I0;
constexpr float F_TAU_AMPA = (float)(2e-3 * D_UT / (D_KAPPA * 20.0 * D_I0));
constexpr float F_TAU_GABA = (float)(2e-3 * D_UT / (D_KAPPA * 5.0 * D_I0));
constexpr float F_TAU_SOMA = (float)(2e-3 * D_UT / (D_KAPPA * 5.0 * D_I0));
constexpr float F_TAU_AHP  = (float)(4e-3 * D_UT / (D_KAPPA * 2.0 * D_I0));
constexpr float F_DPI_TAU  = (float)(5.0 * D_I0);
constexpr float F_RESET    = (float)(1.2 * D_I0);
constexpr float F_VR       = (float)(5.0 * D_I0 + D_I0);
constexpr float F_TH       = (float)(2000.0 * D_I0);
constexpr float F_PFB_TH   = (float)(1000.0 * D_I0);
constexpr float F_ALPHA    = 4.0f;
constexpr float F_AMPA_GAIN = (float)(4.0 * 100.0 * D_I0);
constexpr float F_GABA_GAIN = (float)(4.0 * 100.0 * D_I0);
constexpr float F_AHP_GAIN  = (float)(4.0 * 2.0 * D_I0);
constexpr float F_AHP_JUMP  = (float)(4.0 * D_I0);
constexpr float F_PFB_NORM  = (float)(20.0 * D_I0);
constexpr float F_PFB_GAIN  = (float)(100.0 * D_I0);
constexpr float F_ALPHA_DPI = (float)(4.0 * (5.0 * D_I0));
constexpr float F_DT = 1e-3f;
constexpr float F_INIT_MEM = (float)(1.1 * D_I0);
constexpr float F_INV223 = 1.1920928955078125e-7f;  // 2^-23
constexpr unsigned BIAS_MUL = (1u << 14) + (1u << 22);
}  // namespace

typedef __attribute__((ext_vector_type(4))) int i32x4;

__device__ __forceinline__ void gload_lds16(const void* g, void* l) {
  __builtin_amdgcn_global_load_lds(
      (const __attribute__((address_space(1))) void*)g,
      (__attribute__((address_space(3))) void*)l, 16, 0, 0);
}

#define WAITVM(N) asm volatile("s_waitcnt vmcnt(" #N ")" ::: "memory")

// Chunked WT (granule [fq][fr]): byte w[k][n] ->
// [n>>7]*65536 + (k8>>3)*8192 + ((n>>4)&7)*1024 + ((k8&7)>>1)*256 + (n&15)*16 + (k8&1)*8.
__global__ __launch_bounds__(256) void build_wt(
    const float* __restrict__ Wa, const float* __restrict__ Wg,
    unsigned char* __restrict__ WTa, unsigned char* __restrict__ WTg) {
  const int t = blockIdx.x * 256 + threadIdx.x;  // 65536 threads
  const float* W = (t >> 15) ? Wg : Wa;
  unsigned char* O = (t >> 15) ? WTg : WTa;
  const int r = t & 32767;
  const int n = r >> 6, k8 = r & 63;
  unsigned char b[8];
#pragma unroll
  for (int j = 0; j < 8; ++j)
    b[j] = (unsigned char)(int)rintf(W[(size_t)(k8 * 8 + j) * 512 + n]);
  const size_t addr = (size_t)(n >> 7) * 65536 + (k8 >> 3) * 8192 +
                      ((n >> 4) & 7) * 1024 +
                      ((k8 & 7) >> 1) * 256 + (n & 15) * 16 + (k8 & 1) * 8;
  *(unsigned long long*)(O + addr) = *(unsigned long long*)b;
}

// colsum[z*512+n] = sum_k rint(W_z[k][n]); runs once.
__global__ __launch_bounds__(256) void colsum_w(
    const float* __restrict__ Wa, const float* __restrict__ Wg,
    int* __restrict__ colsum) {
  const int t = blockIdx.x * 256 + threadIdx.x;  // 1024 threads
  const int z = t >> 9, n = t & 511;
  const float* W = z ? Wg : Wa;
  int s = 0;
  for (int k = 0; k < 512; ++k) s += (int)rintf(W[(size_t)k * 512 + n]);
  colsum[t] = s;
}

// split3 (granule [fq][fr]): in-chunk loc = q*256 + rl*16.
// k = rint(x*2^23); p0=k&127, p1=((k>>7)&255)-128, p2=((k>>15)&255)-128.
__global__ __launch_bounds__(256) void split3(
    const float* __restrict__ XA, const float* __restrict__ XG,
    unsigned char* __restrict__ A4a, unsigned char* __restrict__ A4g, int nwpi) {
  const int wid = (blockIdx.x * 256 + threadIdx.x) >> 6;
  const int l = threadIdx.x & 63;
  const float* X = XA;
  unsigned char* O = A4a;
  int w = wid;
  if (w >= nwpi) { X = XG; O = A4g; w -= nwpi; }
  const int rt = w >> 6, rem = w & 63, c = rem >> 3, g = rem & 7;
  const int rl = l >> 2, q = l & 3;
  const float* src = X + (size_t)(rt * 128 + g * 16 + rl) * 512 + c * 64 + q * 16;
  float a[16];
#pragma unroll
  for (int j = 0; j < 4; ++j) {
    const float4 v = *(const float4*)(src + j * 4);
    a[j * 4 + 0] = v.x; a[j * 4 + 1] = v.y; a[j * 4 + 2] = v.z; a[j * 4 + 3] = v.w;
  }
  unsigned int k[16];
#pragma unroll
  for (int e = 0; e < 16; ++e) k[e] = (unsigned int)rintf(a[e] * 8388608.0f);
  unsigned char* base = O + (size_t)rt * 196608 + c * 8192 + g * 1024 + q * 256 + rl * 16;
  unsigned int u[4];
#pragma unroll
  for (int j = 0; j < 4; ++j)
    u[j] = (k[4 * j] & 127u) | ((k[4 * j + 1] & 127u) << 8) |
           ((k[4 * j + 2] & 127u) << 16) | ((k[4 * j + 3] & 127u) << 24);
  *(uint4*)(base) = make_uint4(u[0], u[1], u[2], u[3]);
#pragma unroll
  for (int j = 0; j < 4; ++j)
    u[j] = (((k[4 * j] >> 7) - 128u) & 255u) | ((((k[4 * j + 1] >> 7) - 128u) & 255u) << 8) |
           ((((k[4 * j + 2] >> 7) - 128u) & 255u) << 16) | ((((k[4 * j + 3] >> 7) - 128u) & 255u) << 24);
  *(uint4*)(base + 65536) = make_uint4(u[0], u[1], u[2], u[3]);
#pragma unroll
  for (int j = 0; j < 4; ++j)
    u[j] = (((k[4 * j] >> 15) - 128u) & 255u) | ((((k[4 * j + 1] >> 15) - 128u) & 255u) << 8) |
           ((((k[4 * j + 2] >> 15) - 128u) & 255u) << 16) | ((((k[4 * j + 3] >> 15) - 128u) & 255u) << 24);
  *(uint4*)(base + 131072) = make_uint4(u[0], u[1], u[2], u[3]);
}

// Exact GEMM v10 (R20-verified best, ~130us): quad-buffered LDS, depth-3
// prefetch, raw s_barrier + counted vmcnt (8 steady / 4 / 0 tail).
// INC = RN((digits @ W Horner) + bias) * 2^-23 — bit-identical to rounds 5-22.
__global__ __launch_bounds__(256) void gemm_i8_v10(
    const unsigned char* __restrict__ A4a, const unsigned char* __restrict__ A4g,
    const unsigned char* __restrict__ WTa, const unsigned char* __restrict__ WTg,
    const int* __restrict__ colsum,
    float* __restrict__ INCa, float* __restrict__ INCg, int nwg) {
  __shared__ __align__(16) unsigned char LDS[65536];
  unsigned char* Al = LDS;           // 4 x 8KB A bufs
  unsigned char* Bl = LDS + 32768;   // 4 x 8KB B bufs
  const int bid = blockIdx.x;
  const int L = (bid & 7) * (nwg >> 3) + (bid >> 3);  // nwg % 8 == 0
  const int m = L >> 3, sub = L & 7;
  const int n = sub & 3, z = sub >> 2;
  const unsigned char* A4 = (z ? A4g : A4a) + (size_t)m * 196608;
  const unsigned char* Bg = (z ? WTg : WTa) + (size_t)n * 65536;
  float* C = z ? INCg : INCa;

  const int tid = threadIdx.x;
  const int lane = tid & 63, wave = tid >> 6;
  const int wr = wave >> 1, wc = wave & 1;  // 2x2 waves: 64x64 out each
  const int fr = lane & 15, fq = lane >> 4;
  const int goff = tid * 16;
  const int woff = wave * 1024;
  const int floc = fq * 256 + fr * 16;

#define STAGE(t)                                                            \
  {                                                                         \
    const int aoff_ = (2 - ((t) >> 3)) * 65536 + ((t) & 7) * 8192;          \
    const int boff_ = ((t) & 7) * 8192;                                     \
    const int lb_ = ((t) & 3) * 8192 + woff;                                \
    gload_lds16(A4 + aoff_ + goff, Al + lb_);                               \
    gload_lds16(A4 + aoff_ + 4096 + goff, Al + lb_ + 4096);                 \
    gload_lds16(Bg + boff_ + goff, Bl + lb_);                               \
    gload_lds16(Bg + boff_ + 4096 + goff, Bl + lb_ + 4096);                 \
  }

  STAGE(0) STAGE(1) STAGE(2)

  i32x4 acc[4][4] = {};
#pragma unroll
  for (int s = 0; s < 24; ++s) {
    if (s <= 21) WAITVM(8);
    else if (s == 22) WAITVM(4);
    else WAITVM(0);
    __builtin_amdgcn_s_barrier();
    asm volatile("" ::: "memory");
    __builtin_amdgcn_sched_barrier(0);
    if (s + 3 < 24) STAGE(s + 3)
    {
      const int b = (s & 3) * 8192;
      i32x4 af[4], bf[4];
#pragma unroll
      for (int fm = 0; fm < 4; ++fm)
        af[fm] = *(const i32x4*)&Al[b + (wr * 4 + fm) * 1024 + floc];
#pragma unroll
      for (int fn = 0; fn < 4; ++fn)
        bf[fn] = *(const i32x4*)&Bl[b + (wc * 4 + fn) * 1024 + floc];
#pragma unroll
      for (int fm = 0; fm < 4; ++fm)
#pragma unroll
        for (int fn = 0; fn < 4; ++fn)
          acc[fm][fn] = __builtin_amdgcn_mfma_i32_16x16x64_i8(
              af[fm], bf[fn], acc[fm][fn], 0, 0, 0);
    }
    if (s == 7) {
#pragma unroll
      for (int fm = 0; fm < 4; ++fm)
#pragma unroll
        for (int fn = 0; fn < 4; ++fn) acc[fm][fn] = acc[fm][fn] << 8;
    }
    if (s == 15) {
#pragma unroll
      for (int fm = 0; fm < 4; ++fm)
#pragma unroll
        for (int fn = 0; fn < 4; ++fn) acc[fm][fn] = acc[fm][fn] << 7;
    }
  }
#undef STAGE
  __syncthreads();

  const int crow0 = m * 128 + wr * 64;
  const int ccol0 = n * 128 + wc * 64;
  unsigned bias[4];
#pragma unroll
  for (int fn = 0; fn < 4; ++fn)
    bias[fn] = BIAS_MUL * (unsigned)colsum[z * 512 + ccol0 + fn * 16 + fr];
  float* scratch = (float*)LDS + wave * (16 * 68);
  const int erow = lane >> 4;
  const int ecol = (lane & 15) * 4;
#pragma unroll
  for (int fm = 0; fm < 4; ++fm) {
#pragma unroll
    for (int fn = 0; fn < 4; ++fn)
#pragma unroll
      for (int r = 0; r < 4; ++r) {
        const unsigned tot = (unsigned)acc[fm][fn][r] + bias[fn];
        scratch[(fq * 4 + r) * 68 + fn * 16 + fr] = (float)tot * F_INV223;
      }
    float4 rows[4];
#pragma unroll
    for (int j = 0; j < 4; ++j)
      rows[j] = *(const float4*)&scratch[(erow + 4 * j) * 68 + ecol];
#pragma unroll
    for (int j = 0; j < 4; ++j) {
      const int grow = crow0 + fm * 16 + erow + 4 * j;
      *(float4*)&C[(size_t)grow * NOUT + ccol0 + ecol] = rows[j];
    }
  }
}

// neuron_scan v1 + depth-1 INC prefetch: loads for step t+1 issue before the
// compute of step t (register double-buffer; values & op order unchanged ->
// spikes bit-identical to R20/R22).
__global__ __launch_bounds__(256) void neuron_scan(
    const float* __restrict__ inca, const float* __restrict__ incg,
    float* __restrict__ Sout, float* __restrict__ state, int tc, int first) {
  const int idx = blockIdx.x * 256 + threadIdx.x;
  float mem, ampa, gaba, ahp, refr;
  if (first) {
    mem = F_INIT_MEM; ampa = F_I0; gaba = F_I0; ahp = 0.0f; refr = 0.0f;
  } else {
    mem  = state[idx];
    ampa = state[NEURONS + idx];
    gaba = state[2 * NEURONS + idx];
    ahp  = state[3 * NEURONS + idx];
    refr = state[4 * NEURONS + idx];
  }
  float nxa = inca[idx];
  float nxg = incg[idx];
  for (int t = 0; t < tc; ++t) {
    const float cxa = nxa, cxg = nxg;
    if (t + 1 < tc) {  // prefetch next step's injections (hides ~500cyc)
      nxa = inca[(size_t)(t + 1) * NEURONS + idx];
      nxg = incg[(size_t)(t + 1) * NEURONS + idx];
    }
    const float xa = F_AMPA_GAIN * cxa;
    const float xg = F_GABA_GAIN * cxg;
    const float pfb = F_PFB_GAIN / (1.0f + expf(-(mem - F_PFB_TH) / F_PFB_NORM));
    const float dahp = (-F_AHP_GAIN - ahp) / (F_TAU_AHP * (1.0f + F_AHP_GAIN / ahp));
    const float Iin = fmaxf(ampa - gaba + F_I0, F_I0);
    const float Isum = F_VR + ahp - pfb;
    const float dmem = (F_ALPHA * (Iin - Isum) - Isum * mem / F_DPI_TAU)
                     / (F_TAU_SOMA * (1.0f + F_ALPHA_DPI / mem));
    const float dampa = (F_I0 - ampa) / F_TAU_AMPA;
    ampa = ampa + xa;
    const float dgaba = (F_I0 - gaba) / F_TAU_GABA;
    gaba = gaba + xg;
    refr = refr - (refr > 0.0f ? 1.0f : 0.0f);
    mem = mem + F_DT * dmem * (refr <= 0.0f ? 1.0f : 0.0f);
    ahp = ahp + F_DT * dahp;
    ampa = ampa + F_DT * dampa;
    gaba = gaba + F_DT * dgaba;
    const float S = (mem - F_TH) > 0.0f ? 1.0f : 0.0f;
    refr = refr + floorf(S * 5.0f);
    ahp = ahp + F_AHP_JUMP * S;
    mem = F_RESET * S + mem * (1.0f - S);
    mem = fmaxf(mem, F_I0);
    Sout[(size_t)t * NEURONS + idx] = S;
  }
  state[idx] = mem;
  state[NEURONS + idx] = ampa;
  state[2 * NEURONS + idx] = gaba;
  state[3 * NEURONS + idx] = ahp;
  state[4 * NEURONS + idx] = refr;
}

extern "C" void kernel_launch(void* const* d_in, const int* in_sizes, int n_in,
                              void* d_out, int out_size, void* d_ws, size_t ws_size,
                              hipStream_t stream) {
  const float* XA = (const float*)d_in[0];
  const float* XG = (const float*)d_in[1];
  const float* WA = (const float*)d_in[2];
  const float* WG = (const float*)d_in[3];
  float* S = (float*)d_out;

  int tc = 1;
  const int cands[8] = {100, 50, 25, 20, 10, 5, 2, 1};
  for (int i = 0; i < 8; ++i) {
    const size_t need = 5771264ull + (size_t)cands[i] * 3670016ull;
    if (need <= ws_size) { tc = cands[i]; break; }
  }

  unsigned char* WTa = (unsigned char*)d_ws;
  unsigned char* WTg = WTa + (size_t)NOUT * 512;
  int* colsum = (int*)(WTg + (size_t)NOUT * 512);
  unsigned char* A4a = (unsigned char*)(colsum + 1024);
  unsigned char* A4g = A4a + (size_t)tc * B * K3B;
  float* INCa  = (float*)(A4g + (size_t)tc * B * K3B);
  float* INCg  = INCa + (size_t)tc * NEURONS;
  float* state = INCg + (size_t)tc * NEURONS;

  build_wt<<<256, 256, 0, stream>>>(WA, WG, WTa, WTg);
  colsum_w<<<4, 256, 0, stream>>>(WA, WG, colsum);

  const int nwpi = tc * 256;              // split waves per input
  const int splitBlocks = nwpi / 2;       // 2 inputs, 4 waves/block
  const int nm = tc * B / 128;            // 128-row m-tiles
  const int nwg = nm * 8;                 // x4 n-tiles x2 z
  const int nch = TT / tc;
  for (int c = 0; c < nch; ++c) {
    const size_t inOff = (size_t)c * tc * B * NIN;
    split3<<<splitBlocks, 256, 0, stream>>>(XA + inOff, XG + inOff, A4a, A4g, nwpi);
    gemm_i8_v10<<<nwg, 256, 0, stream>>>(A4a, A4g, WTa, WTg, colsum, INCa, INCg, nwg);
    neuron_scan<<<NEURONS / 256, 256, 0, stream>>>(
        INCa, INCg, S + (size_t)c * tc * NEURONS, state, tc, c == 0 ? 1 : 0);
  }
}